// Round 6
// baseline (280.297 us; speedup 1.0000x reference)
//
#include <hip/hip_runtime.h>

#define N_NODES 100000
#define N_EDGES 400000
#define D 128
#define BN_EPS 1e-5f
#define ELL_CAP 32

// ===== primary (ELL2/bf16) ws layout, 4B units — ~51.6 MB =====
// stats and deg adjacent -> single memset zeroes both.
#define WS_STATS    0                                 // 256 floats
#define WS_DEG2     256                               // 100000 ints
#define WS_HB       (WS_DEG2 + N_NODES)               // N*D bf16 = 6.4M float slots
#define WS_ELL2     (WS_HB + N_NODES * D / 2)         // N*ELL_CAP int2
#define WS_ELL2_END (WS_ELL2 + N_NODES * ELL_CAP * 2)
// ===== CSR fallback layout (proven R3; mutually exclusive with primary) =====
#define WS_SCALE   256
#define WS_SHIFT   384
#define WS_WT      512
#define WS_H       16896
#define WS_DEG     (WS_H + N_NODES * D)
#define WS_ROWPTR  (WS_DEG + N_NODES)
#define WS_CURSOR  (WS_ROWPTR + N_NODES + 1)
#define WS_CSRCOL  (WS_CURSOR + N_NODES)
#define WS_CSRW    (WS_CSRCOL + N_EDGES)
#define WS_END     (WS_CSRW + N_EDGES)

#define CS_BLOCKS   1024
#define FILL_BLOCKS ((N_EDGES + 255) / 256)

typedef __attribute__((ext_vector_type(8))) short short8;
typedef __attribute__((ext_vector_type(4))) float f32x4;

static __device__ __forceinline__ unsigned short f2bf(float f) {
    union { float f; unsigned u; } v; v.f = f;
    unsigned r = v.u + 0x7FFF + ((v.u >> 16) & 1);   // RNE
    return (unsigned short)(r >> 16);
}
static __device__ __forceinline__ float bf2f(unsigned short b) {
    union { unsigned u; float f; } v; v.u = ((unsigned)b) << 16;
    return v.f;
}

// ---------------- prep: block-specialized colstats + ELL fill ----------------
// blocks [0, CS_BLOCKS): column sums/sumsq with 4-stream ILP (R5: 512 blocks,
// ~1.5 outstanding loads/CU -> 432 GB/s latency-bound; this gives 16 waves/CU
// with 4 loads in flight each). blocks [CS_BLOCKS, +FILL_BLOCKS): ELL build.
__global__ __launch_bounds__(256) void prep_kernel(const float* __restrict__ x,
                                                   float* __restrict__ stats,
                                                   const int* __restrict__ ei,
                                                   const float* __restrict__ ew,
                                                   int* __restrict__ deg,
                                                   int2* __restrict__ ell2) {
    if (blockIdx.x >= CS_BLOCKS) {
        int e = (blockIdx.x - CS_BLOCKS) * 256 + threadIdx.x;
        if (e >= N_EDGES) return;
        int r = ei[e];
        int c = ei[N_EDGES + e];
        float w = ew[e];
        int slot = atomicAdd(&deg[r], 1);
        if (slot < ELL_CAP) ell2[r * ELL_CAP + slot] = make_int2(c, __float_as_int(w));
        return;
    }

    const int nthreads = CS_BLOCKS * 256;            // 262144; *4 multiple of 128
    int tid = blockIdx.x * 256 + threadIdx.x;
    const float4* x4 = (const float4*)x;
    const int total4 = N_NODES * D / 4;              // 3,200,000
    float4 s = {0.f, 0.f, 0.f, 0.f};
    float4 q = {0.f, 0.f, 0.f, 0.f};
    int i = tid;
    // 4 independent loads in flight per iteration
    for (; i + 3 * nthreads < total4; i += 4 * nthreads) {
        float4 v0 = x4[i];
        float4 v1 = x4[i + nthreads];
        float4 v2 = x4[i + 2 * nthreads];
        float4 v3 = x4[i + 3 * nthreads];
        s.x += v0.x; s.y += v0.y; s.z += v0.z; s.w += v0.w;
        q.x += v0.x * v0.x; q.y += v0.y * v0.y; q.z += v0.z * v0.z; q.w += v0.w * v0.w;
        s.x += v1.x; s.y += v1.y; s.z += v1.z; s.w += v1.w;
        q.x += v1.x * v1.x; q.y += v1.y * v1.y; q.z += v1.z * v1.z; q.w += v1.w * v1.w;
        s.x += v2.x; s.y += v2.y; s.z += v2.z; s.w += v2.w;
        q.x += v2.x * v2.x; q.y += v2.y * v2.y; q.z += v2.z * v2.z; q.w += v2.w * v2.w;
        s.x += v3.x; s.y += v3.y; s.z += v3.z; s.w += v3.w;
        q.x += v3.x * v3.x; q.y += v3.y * v3.y; q.z += v3.z * v3.z; q.w += v3.w * v3.w;
    }
    for (; i < total4; i += nthreads) {
        float4 v = x4[i];
        s.x += v.x; s.y += v.y; s.z += v.z; s.w += v.w;
        q.x += v.x * v.x; q.y += v.y * v.y; q.z += v.z * v.z; q.w += v.w * v.w;
    }
    __shared__ float4 ss[256];
    __shared__ float4 sq[256];
    ss[threadIdx.x] = s;
    sq[threadIdx.x] = q;
    __syncthreads();
    if (threadIdx.x < 32) {
        float4 a = ss[threadIdx.x];
        float4 b = sq[threadIdx.x];
        for (int j = 32; j < 256; j += 32) {
            float4 t1 = ss[threadIdx.x + j];
            float4 t2 = sq[threadIdx.x + j];
            a.x += t1.x; a.y += t1.y; a.z += t1.z; a.w += t1.w;
            b.x += t2.x; b.y += t2.y; b.z += t2.z; b.w += t2.w;
        }
        int colb = (threadIdx.x * 4) & 127;
        atomicAdd(&stats[colb + 0], a.x);
        atomicAdd(&stats[colb + 1], a.y);
        atomicAdd(&stats[colb + 2], a.z);
        atomicAdd(&stats[colb + 3], a.w);
        atomicAdd(&stats[128 + colb + 0], b.x);
        atomicAdd(&stats[128 + colb + 1], b.y);
        atomicAdd(&stats[128 + colb + 2], b.z);
        atomicAdd(&stats[128 + colb + 3], b.w);
    }
}

// ---------------- MFMA gemm: BN(finalize fused) + ReLU + GEMM -> hb only -----
#define YPAD 136
#define OPAD 132
__global__ __launch_bounds__(256) void gemm_mfma2_kernel(const float* __restrict__ x,
                                                         const float* __restrict__ stats,
                                                         const float* __restrict__ gamma,
                                                         const float* __restrict__ beta,
                                                         const float* __restrict__ W,
                                                         unsigned short* __restrict__ hb) {
    __shared__ __align__(16) unsigned char smem[52224];  // max(W 34816 + Y 17408, Outs 33792)
    __shared__ float sscale[128];
    __shared__ float sshift[128];
    unsigned short* Wl = (unsigned short*)smem;                    // [128][YPAD]
    unsigned short* Yl = (unsigned short*)(smem + 128 * YPAD * 2); // [64][YPAD]
    float* Outs = (float*)smem;                                    // [64][OPAD]

    int t = threadIdx.x;
    int row0 = blockIdx.x * 64;

    if (t < 128) {
        float mu  = stats[t] * (1.0f / N_NODES);
        float var = stats[128 + t] * (1.0f / N_NODES) - mu * mu;
        float sc  = gamma[t] * rsqrtf(var + BN_EPS);
        sscale[t] = sc;
        sshift[t] = beta[t] - mu * sc;
    }
    __syncthreads();

    for (int i = t; i < 2048; i += 256) {
        int n  = i >> 4;
        int k8 = (i & 15) * 8;
        float4 w0 = *(const float4*)(W + n * 128 + k8);
        float4 w1 = *(const float4*)(W + n * 128 + k8 + 4);
        short8 p;
        p[0] = (short)f2bf(w0.x); p[1] = (short)f2bf(w0.y);
        p[2] = (short)f2bf(w0.z); p[3] = (short)f2bf(w0.w);
        p[4] = (short)f2bf(w1.x); p[5] = (short)f2bf(w1.y);
        p[6] = (short)f2bf(w1.z); p[7] = (short)f2bf(w1.w);
        *(short8*)(Wl + n * YPAD + k8) = p;
    }
    for (int i = t; i < 64 * 32; i += 256) {
        int r  = i >> 5;
        int c4 = (i & 31) * 4;
        int grow = row0 + r;
        int srow = grow < N_NODES ? grow : N_NODES - 1;
        float4 v = *(const float4*)(x + (size_t)srow * D + c4);
        float a0 = fmaxf(fmaf(v.x, sscale[c4 + 0], sshift[c4 + 0]), 0.f);
        float a1 = fmaxf(fmaf(v.y, sscale[c4 + 1], sshift[c4 + 1]), 0.f);
        float a2 = fmaxf(fmaf(v.z, sscale[c4 + 2], sshift[c4 + 2]), 0.f);
        float a3 = fmaxf(fmaf(v.w, sscale[c4 + 3], sshift[c4 + 3]), 0.f);
        ushort4 b;
        b.x = f2bf(a0); b.y = f2bf(a1); b.z = f2bf(a2); b.w = f2bf(a3);
        *(ushort4*)(Yl + r * YPAD + c4) = b;
    }
    __syncthreads();

    int lane = t & 63;
    int wave = t >> 6;
    int m16  = lane & 15;
    int quad = lane >> 4;
    int wrow0 = wave * 16;

    f32x4 acc[8];
    #pragma unroll
    for (int nt = 0; nt < 8; nt++) acc[nt] = (f32x4){0.f, 0.f, 0.f, 0.f};

    #pragma unroll
    for (int kc = 0; kc < 4; kc++) {
        short8 a = *(const short8*)(Yl + (wrow0 + m16) * YPAD + kc * 32 + quad * 8);
        #pragma unroll
        for (int nt = 0; nt < 8; nt++) {
            short8 b = *(const short8*)(Wl + (nt * 16 + m16) * YPAD + kc * 32 + quad * 8);
            acc[nt] = __builtin_amdgcn_mfma_f32_16x16x32_bf16(a, b, acc[nt], 0, 0, 0);
        }
    }
    __syncthreads();

    #pragma unroll
    for (int nt = 0; nt < 8; nt++) {
        #pragma unroll
        for (int r = 0; r < 4; r++) {
            Outs[(wrow0 + quad * 4 + r) * OPAD + nt * 16 + m16] = acc[nt][r];
        }
    }
    __syncthreads();

    for (int i = t; i < 64 * 32; i += 256) {
        int r  = i >> 5;
        int c4 = (i & 31) * 4;
        int grow = row0 + r;
        if (grow < N_NODES) {
            float4 v = *(const float4*)(Outs + r * OPAD + c4);
            ushort4 hb4;
            hb4.x = f2bf(v.x); hb4.y = f2bf(v.y); hb4.z = f2bf(v.z); hb4.w = f2bf(v.w);
            *(ushort4*)(hb + (size_t)grow * D + c4) = hb4;
        }
    }
}

// ---------------- gather: acc + h*h (from bf16), single out write ------------
__global__ __launch_bounds__(256) void gather_ell2_kernel(const int* __restrict__ deg,
                                                          const int2* __restrict__ ell2,
                                                          const unsigned short* __restrict__ hb,
                                                          float* __restrict__ out) {
    int lane = threadIdx.x & 31;
    int n = blockIdx.x * 8 + (threadIdx.x >> 5);
    if (n >= N_NODES) return;
    int dg = deg[n];
    if (dg > ELL_CAP) dg = ELL_CAP;
    float4 acc = {0.f, 0.f, 0.f, 0.f};
    #pragma unroll 2
    for (int s = 0; s < dg; s++) {
        int2 cw = ell2[n * ELL_CAP + s];          // broadcast within group
        float w = __int_as_float(cw.y);
        ushort4 hv = *(const ushort4*)(hb + (size_t)cw.x * D + lane * 4);
        acc.x = fmaf(w, bf2f(hv.x), acc.x);
        acc.y = fmaf(w, bf2f(hv.y), acc.y);
        acc.z = fmaf(w, bf2f(hv.z), acc.z);
        acc.w = fmaf(w, bf2f(hv.w), acc.w);
    }
    ushort4 hs = *(const ushort4*)(hb + (size_t)n * D + lane * 4);
    float h0 = bf2f(hs.x), h1 = bf2f(hs.y), h2 = bf2f(hs.z), h3 = bf2f(hs.w);
    float4 o;
    o.x = fmaf(h0, h0, acc.x);
    o.y = fmaf(h1, h1, acc.y);
    o.z = fmaf(h2, h2, acc.z);
    o.w = fmaf(h3, h3, acc.w);
    *(float4*)&out[(size_t)n * D + lane * 4] = o;
}

// ================= CSR / scatter fallback path (proven R3) =================
__global__ __launch_bounds__(256) void colstats_kernel(const float* __restrict__ x,
                                                       float* __restrict__ stats) {
    int tid = blockIdx.x * blockDim.x + threadIdx.x;
    int nthreads = gridDim.x * blockDim.x;
    const float4* x4 = (const float4*)x;
    const int total4 = N_NODES * D / 4;
    float4 s = {0.f, 0.f, 0.f, 0.f};
    float4 q = {0.f, 0.f, 0.f, 0.f};
    for (int i = tid; i < total4; i += nthreads) {
        float4 v = x4[i];
        s.x += v.x; s.y += v.y; s.z += v.z; s.w += v.w;
        q.x += v.x * v.x; q.y += v.y * v.y; q.z += v.z * v.z; q.w += v.w * v.w;
    }
    __shared__ float4 ss[256];
    __shared__ float4 sq[256];
    ss[threadIdx.x] = s;
    sq[threadIdx.x] = q;
    __syncthreads();
    if (threadIdx.x < 32) {
        float4 a = ss[threadIdx.x];
        float4 b = sq[threadIdx.x];
        for (int i = 32; i < 256; i += 32) {
            float4 t1 = ss[threadIdx.x + i];
            float4 t2 = sq[threadIdx.x + i];
            a.x += t1.x; a.y += t1.y; a.z += t1.z; a.w += t1.w;
            b.x += t2.x; b.y += t2.y; b.z += t2.z; b.w += t2.w;
        }
        int colb = (threadIdx.x * 4) & 127;
        atomicAdd(&stats[colb + 0], a.x);
        atomicAdd(&stats[colb + 1], a.y);
        atomicAdd(&stats[colb + 2], a.z);
        atomicAdd(&stats[colb + 3], a.w);
        atomicAdd(&stats[128 + colb + 0], b.x);
        atomicAdd(&stats[128 + colb + 1], b.y);
        atomicAdd(&stats[128 + colb + 2], b.z);
        atomicAdd(&stats[128 + colb + 3], b.w);
    }
}

__global__ __launch_bounds__(128) void finalize_kernel(const float* __restrict__ stats,
                                                       const float* __restrict__ gamma,
                                                       const float* __restrict__ beta,
                                                       float* __restrict__ scale,
                                                       float* __restrict__ shift) {
    int d = threadIdx.x;
    float mu  = stats[d] * (1.0f / N_NODES);
    float var = stats[128 + d] * (1.0f / N_NODES) - mu * mu;
    float sc  = gamma[d] * rsqrtf(var + BN_EPS);
    scale[d] = sc;
    shift[d] = beta[d] - mu * sc;
}

__global__ __launch_bounds__(256) void transposeW_kernel(const float* __restrict__ W,
                                                         float* __restrict__ Wt) {
    int i = blockIdx.x * blockDim.x + threadIdx.x;
    if (i < D * D) {
        int j = i >> 7;
        int k = i & 127;
        Wt[k * D + j] = W[i];
    }
}

template <int WRITE_SQ>
__global__ __launch_bounds__(256) void gemm_kernel(const float* __restrict__ x,
                                                   const float* __restrict__ scale,
                                                   const float* __restrict__ shift,
                                                   const float* __restrict__ Wt,
                                                   float* __restrict__ h,
                                                   float* __restrict__ out) {
    __shared__ float Ws[D * D];
    __shared__ float Ys[32 * D];
    int t = threadIdx.x;
    const float4* Wt4 = (const float4*)Wt;
    float4* Ws4 = (float4*)Ws;
    #pragma unroll 4
    for (int i = t; i < D * D / 4; i += 256) Ws4[i] = Wt4[i];
    int row0 = blockIdx.x * 32;
    const float4* x4 = (const float4*)(x + (size_t)row0 * D);
    float4* Ys4 = (float4*)Ys;
    #pragma unroll 2
    for (int i = t; i < 32 * D / 4; i += 256) {
        int c4 = (i & 31) * 4;
        float4 v = x4[i];
        v.x = fmaxf(fmaf(v.x, scale[c4 + 0], shift[c4 + 0]), 0.f);
        v.y = fmaxf(fmaf(v.y, scale[c4 + 1], shift[c4 + 1]), 0.f);
        v.z = fmaxf(fmaf(v.z, scale[c4 + 2], shift[c4 + 2]), 0.f);
        v.w = fmaxf(fmaf(v.w, scale[c4 + 3], shift[c4 + 3]), 0.f);
        Ys4[i] = v;
    }
    __syncthreads();
    int cg = t & 31;
    int rg = t >> 5;
    float4 acc[4] = {{0,0,0,0},{0,0,0,0},{0,0,0,0},{0,0,0,0}};
    #pragma unroll 2
    for (int k = 0; k < D; k += 4) {
        float4 w0 = *(const float4*)&Ws[(k + 0) * D + cg * 4];
        float4 w1 = *(const float4*)&Ws[(k + 1) * D + cg * 4];
        float4 w2 = *(const float4*)&Ws[(k + 2) * D + cg * 4];
        float4 w3 = *(const float4*)&Ws[(k + 3) * D + cg * 4];
        #pragma unroll
        for (int r = 0; r < 4; r++) {
            float4 y = *(const float4*)&Ys[(rg * 4 + r) * D + k];
            acc[r].x = fmaf(y.x, w0.x, fmaf(y.y, w1.x, fmaf(y.z, w2.x, fmaf(y.w, w3.x, acc[r].x))));
            acc[r].y = fmaf(y.x, w0.y, fmaf(y.y, w1.y, fmaf(y.z, w2.y, fmaf(y.w, w3.y, acc[r].y))));
            acc[r].z = fmaf(y.x, w0.z, fmaf(y.y, w1.z, fmaf(y.z, w2.z, fmaf(y.w, w3.z, acc[r].z))));
            acc[r].w = fmaf(y.x, w0.w, fmaf(y.y, w1.w, fmaf(y.z, w2.w, fmaf(y.w, w3.w, acc[r].w))));
        }
    }
    #pragma unroll
    for (int r = 0; r < 4; r++) {
        size_t row = (size_t)row0 + rg * 4 + r;
        float4 v = acc[r];
        *(float4*)&h[row * D + cg * 4] = v;
        if (WRITE_SQ) {
            float4 sqv = {v.x * v.x, v.y * v.y, v.z * v.z, v.w * v.w};
            *(float4*)&out[row * D + cg * 4] = sqv;
        }
    }
}

__global__ __launch_bounds__(256) void hist_kernel(const int* __restrict__ ei,
                                                   int* __restrict__ deg) {
    int e = blockIdx.x * 256 + threadIdx.x;
    if (e < N_EDGES) atomicAdd(&deg[ei[e]], 1);
}

__global__ __launch_bounds__(1024) void scan_kernel(const int* __restrict__ deg,
                                                    int* __restrict__ row_ptr,
                                                    int* __restrict__ cursor) {
    __shared__ int part[1024];
    int t = threadIdx.x;
    const int CHUNK = 100;
    int base = t * CHUNK;
    int s = 0;
    if (base < N_NODES) {
        for (int i = 0; i < CHUNK; i++) s += deg[base + i];
    }
    part[t] = s;
    __syncthreads();
    for (int off = 1; off < 1024; off <<= 1) {
        int v = (t >= off) ? part[t - off] : 0;
        __syncthreads();
        part[t] += v;
        __syncthreads();
    }
    int pre = (t == 0) ? 0 : part[t - 1];
    if (base < N_NODES) {
        for (int i = 0; i < CHUNK; i++) {
            row_ptr[base + i] = pre;
            cursor[base + i] = pre;
            pre += deg[base + i];
        }
    }
    if (t == 1023) row_ptr[N_NODES] = part[1023];
}

__global__ __launch_bounds__(256) void fill_kernel(const int* __restrict__ ei,
                                                   const float* __restrict__ ew,
                                                   int* __restrict__ cursor,
                                                   int* __restrict__ csr_col,
                                                   float* __restrict__ csr_w) {
    int e = blockIdx.x * 256 + threadIdx.x;
    if (e >= N_EDGES) return;
    int r = ei[e];
    int c = ei[N_EDGES + e];
    int slot = atomicAdd(&cursor[r], 1);
    csr_col[slot] = c;
    csr_w[slot] = ew[e];
}

__global__ __launch_bounds__(256) void gather_kernel(const int* __restrict__ row_ptr,
                                                     const int* __restrict__ csr_col,
                                                     const float* __restrict__ csr_w,
                                                     const float* __restrict__ h,
                                                     float* __restrict__ out) {
    int lane = threadIdx.x & 31;
    int n = blockIdx.x * 8 + (threadIdx.x >> 5);
    if (n >= N_NODES) return;
    int s0 = row_ptr[n];
    int s1 = row_ptr[n + 1];
    float4 acc = {0.f, 0.f, 0.f, 0.f};
    for (int s = s0; s < s1; s++) {
        int c = csr_col[s];
        float w = csr_w[s];
        float4 v = *(const float4*)&h[(size_t)c * D + lane * 4];
        acc.x = fmaf(w, v.x, acc.x);
        acc.y = fmaf(w, v.y, acc.y);
        acc.z = fmaf(w, v.z, acc.z);
        acc.w = fmaf(w, v.w, acc.w);
    }
    float4 hv = *(const float4*)&h[(size_t)n * D + lane * 4];
    float4 o;
    o.x = fmaf(hv.x, hv.x, acc.x);
    o.y = fmaf(hv.y, hv.y, acc.y);
    o.z = fmaf(hv.z, hv.z, acc.z);
    o.w = fmaf(hv.w, hv.w, acc.w);
    *(float4*)&out[(size_t)n * D + lane * 4] = o;
}

__global__ __launch_bounds__(256) void scatter_kernel(const int* __restrict__ ei,
                                                      const float* __restrict__ ew,
                                                      const float* __restrict__ h,
                                                      float* __restrict__ out) {
    int lane = threadIdx.x & 31;
    int e = blockIdx.x * 8 + (threadIdx.x >> 5);
    if (e >= N_EDGES) return;
    int r = ei[e];
    int c = ei[N_EDGES + e];
    float w = ew[e];
    float4 v = *(const float4*)&h[(size_t)c * D + lane * 4];
    float* o = out + (size_t)r * D + lane * 4;
    atomicAdd(o + 0, v.x * w);
    atomicAdd(o + 1, v.y * w);
    atomicAdd(o + 2, v.z * w);
    atomicAdd(o + 3, v.w * w);
}

extern "C" void kernel_launch(void* const* d_in, const int* in_sizes, int n_in,
                              void* d_out, int out_size, void* d_ws, size_t ws_size,
                              hipStream_t stream) {
    const float* n_feat = (const float*)d_in[0];
    const int*   ei     = (const int*)d_in[1];
    const float* ew     = (const float*)d_in[2];
    const float* gamma  = (const float*)d_in[3];
    const float* beta   = (const float*)d_in[4];
    const float* W      = (const float*)d_in[5];
    float* out = (float*)d_out;

    float* ws    = (float*)d_ws;
    float* stats = ws + WS_STATS;

    bool ell_ok = ws_size >= (size_t)WS_ELL2_END * sizeof(float);
    bool csr_ok = ws_size >= (size_t)WS_END * sizeof(float);

    if (ell_ok) {
        int*  deg  = (int*)ws + WS_DEG2;
        unsigned short* hb = (unsigned short*)(ws + WS_HB);
        int2* ell2 = (int2*)((int*)ws + WS_ELL2);

        // one memset zeroes stats (256 f) + deg (100000 i): adjacent
        hipMemsetAsync(stats, 0, (256 + N_NODES) * sizeof(float), stream);
        prep_kernel<<<CS_BLOCKS + FILL_BLOCKS, 256, 0, stream>>>(n_feat, stats, ei, ew, deg, ell2);
        gemm_mfma2_kernel<<<(N_NODES + 63) / 64, 256, 0, stream>>>(n_feat, stats, gamma, beta, W, hb);
        gather_ell2_kernel<<<(N_NODES + 7) / 8, 256, 0, stream>>>(deg, ell2, hb, out);
    } else if (csr_ok) {
        float* scale = ws + WS_SCALE;
        float* shift = ws + WS_SHIFT;
        float* Wt    = ws + WS_WT;
        float* h     = ws + WS_H;
        int*   deg     = (int*)ws + WS_DEG;
        int*   row_ptr = (int*)ws + WS_ROWPTR;
        int*   cursor  = (int*)ws + WS_CURSOR;
        int*   csr_col = (int*)ws + WS_CSRCOL;
        float* csr_w   = ws + WS_CSRW;

        hipMemsetAsync(stats, 0, 256 * sizeof(float), stream);
        colstats_kernel<<<512, 256, 0, stream>>>(n_feat, stats);
        finalize_kernel<<<1, 128, 0, stream>>>(stats, gamma, beta, scale, shift);
        transposeW_kernel<<<64, 256, 0, stream>>>(W, Wt);
        hipMemsetAsync(deg, 0, N_NODES * sizeof(int), stream);
        gemm_kernel<0><<<N_NODES / 32, 256, 0, stream>>>(n_feat, scale, shift, Wt, h, out);
        hist_kernel<<<(N_EDGES + 255) / 256, 256, 0, stream>>>(ei, deg);
        scan_kernel<<<1, 1024, 0, stream>>>(deg, row_ptr, cursor);
        fill_kernel<<<(N_EDGES + 255) / 256, 256, 0, stream>>>(ei, ew, cursor, csr_col, csr_w);
        gather_kernel<<<(N_NODES + 7) / 8, 256, 0, stream>>>(row_ptr, csr_col, csr_w, h, out);
    } else {
        float* scale = ws + WS_SCALE;
        float* shift = ws + WS_SHIFT;
        float* Wt    = ws + WS_WT;
        float* h     = ws + WS_H;
        hipMemsetAsync(stats, 0, 256 * sizeof(float), stream);
        colstats_kernel<<<512, 256, 0, stream>>>(n_feat, stats);
        finalize_kernel<<<1, 128, 0, stream>>>(stats, gamma, beta, scale, shift);
        transposeW_kernel<<<64, 256, 0, stream>>>(W, Wt);
        gemm_kernel<1><<<N_NODES / 32, 256, 0, stream>>>(n_feat, scale, shift, Wt, h, out);
        scatter_kernel<<<(N_EDGES + 7) / 8, 256, 0, stream>>>(ei, ew, h, out);
    }
}